// Round 1
// baseline (525.597 us; speedup 1.0000x reference)
//
#include <hip/hip_runtime.h>
#include <cstddef>

// Problem constants (fixed by setup_inputs)
#define BB 4
#define QQ 4096
#define CC 256
#define MM 8
#define LL 4
#define PP 4
#define DD 32
#define NN 21760

// ---------------------------------------------------------------------------
// Tiled fp32 GEMM:  C[z*tokens + row, col] = A[z*tokens + row, :] @ Bm[:, col] + bias[col]
// STORE_MODE 0: row-major [Z*tokens, Ncols]
// STORE_MODE 1: v_p layout [(z*8 + col/32)*tokens + row]*32 + col%32
// Tile 64x64, BK=16, 256 threads, 4x4 microtile.
// ---------------------------------------------------------------------------
template<int STORE_MODE>
__global__ __launch_bounds__(256) void gemm_tile(
    const float* __restrict__ A,
    const float* __restrict__ Bm,
    const float* __restrict__ bias,
    float* __restrict__ C,
    int tokens, int Ncols, int K)
{
    const int z = blockIdx.z;
    const int row0 = blockIdx.y * 64;
    const int col0 = blockIdx.x * 64;
    const float* Ab = A + (size_t)z * tokens * K;

    __shared__ float As[16][68];
    __shared__ float Bs[16][64];

    const int tid = threadIdx.x;
    const int tx = tid & 15, ty = tid >> 4;

    float acc[4][4] = {};

    for (int k0 = 0; k0 < K; k0 += 16) {
        // A tile: 64 rows x 16 k  (one float4 per thread, stored transposed)
        {
            const int r  = tid >> 2;         // 0..63
            const int kk = (tid & 3) * 4;    // 0,4,8,12
            const float4 av = *(const float4*)(Ab + (size_t)(row0 + r) * K + k0 + kk);
            As[kk + 0][r] = av.x;
            As[kk + 1][r] = av.y;
            As[kk + 2][r] = av.z;
            As[kk + 3][r] = av.w;
        }
        // B tile: 16 k x 64 cols (one float4 per thread)
        {
            const int kk = tid >> 4;         // 0..15
            const int c  = (tid & 15) * 4;
            *(float4*)&Bs[kk][c] = *(const float4*)(Bm + (size_t)(k0 + kk) * Ncols + col0 + c);
        }
        __syncthreads();
        #pragma unroll
        for (int kk = 0; kk < 16; ++kk) {
            float a[4], bv[4];
            #pragma unroll
            for (int j = 0; j < 4; ++j) a[j] = As[kk][ty * 4 + j];
            #pragma unroll
            for (int i = 0; i < 4; ++i) bv[i] = Bs[kk][tx * 4 + i];
            #pragma unroll
            for (int j = 0; j < 4; ++j)
                #pragma unroll
                for (int i = 0; i < 4; ++i)
                    acc[j][i] += a[j] * bv[i];
        }
        __syncthreads();
    }

    #pragma unroll
    for (int j = 0; j < 4; ++j) {
        const int r = row0 + ty * 4 + j;
        const int c = col0 + tx * 4;
        float4 o;
        o.x = acc[j][0] + bias[c + 0];
        o.y = acc[j][1] + bias[c + 1];
        o.z = acc[j][2] + bias[c + 2];
        o.w = acc[j][3] + bias[c + 3];
        if (STORE_MODE == 0) {
            *(float4*)(C + ((size_t)z * tokens + r) * Ncols + c) = o;
        } else {
            const int m = c >> 5, dd = c & 31;
            *(float4*)(C + (((size_t)z * 8 + m) * tokens + r) * 32 + dd) = o;
        }
    }
}

// ---------------------------------------------------------------------------
// Fused softmax + bilinear sampling.
// One block per (b,q), 256 threads: thread = (m = tid>>5, d = tid&31).
// Reads precomputed attn logits [B*Q,128], offsets [B*Q,256], ref points.
// Writes mid[B*Q, 256] with channel = m*32 + d.
// ---------------------------------------------------------------------------
__global__ __launch_bounds__(256) void sampler(
    const float* __restrict__ vp,     // [B,8,N,32]
    const float* __restrict__ gattn,  // [B*Q,128] logits
    const float* __restrict__ goff,   // [B*Q,256] offsets
    const float* __restrict__ pref,   // [B,Q,4,2]
    float* __restrict__ mid)          // [B*Q,256]
{
    const int bq = blockIdx.x;
    const int b = bq >> 12;           // Q = 4096
    const int tid = threadIdx.x;

    __shared__ float s_attn[128];
    __shared__ float s_off[256];
    __shared__ float s_p[8];

    if (tid < 128) s_attn[tid] = gattn[(size_t)bq * 128 + tid];
    s_off[tid] = goff[(size_t)bq * 256 + tid];
    if (tid < 8) s_p[tid] = pref[(size_t)bq * 8 + tid];
    __syncthreads();

    if (tid < 8) {
        const int mh = tid;
        float mx = -1e30f;
        #pragma unroll
        for (int i = 0; i < 16; ++i) mx = fmaxf(mx, s_attn[mh * 16 + i]);
        float sum = 0.f;
        #pragma unroll
        for (int i = 0; i < 16; ++i) {
            const float e = __expf(s_attn[mh * 16 + i] - mx);
            s_attn[mh * 16 + i] = e;
            sum += e;
        }
        const float inv = 1.f / sum;
        #pragma unroll
        for (int i = 0; i < 16; ++i) s_attn[mh * 16 + i] *= inv;
    }
    __syncthreads();

    const int m = tid >> 5, d = tid & 31;
    const float* vpm = vp + (((size_t)b * 8 + m) * NN) * 32 + d;

    const int   Hs[4]   = {128, 64, 32, 16};
    const int   base_[4] = {0, 16384, 20480, 21504};

    float acc = 0.f;
    #pragma unroll
    for (int l = 0; l < 4; ++l) {
        const int Hi = Hs[l], Wi = Hs[l];
        const float Hf = (float)Hi, Wf = (float)Wi;
        const float px = s_p[l * 2 + 0], py = s_p[l * 2 + 1];
        const int base = base_[l];
        #pragma unroll
        for (int pt = 0; pt < 4; ++pt) {
            const int s = (m * 4 + l) * 4 + pt;
            const float a = s_attn[m * 16 + l * 4 + pt];
            const float ox = s_off[s * 2 + 0], oy = s_off[s * 2 + 1];
            const float x = (px + ox / Wf) * Wf - 0.5f;
            const float y = (py + oy / Hf) * Hf - 0.5f;
            const float x0f = floorf(x), y0f = floorf(y);
            const float lx = x - x0f, ly = y - y0f;
            const int x0 = (int)x0f, y0 = (int)y0f;
            const float w00 = (1.f - lx) * (1.f - ly);
            const float w10 = lx * (1.f - ly);
            const float w01 = (1.f - lx) * ly;
            const float w11 = lx * ly;
            const bool vx0 = (x0 >= 0) && (x0 < Wi);
            const bool vx1 = (x0 + 1 >= 0) && (x0 + 1 < Wi);
            const bool vy0 = (y0 >= 0) && (y0 < Hi);
            const bool vy1 = (y0 + 1 >= 0) && (y0 + 1 < Hi);
            const int cx0 = min(max(x0, 0), Wi - 1);
            const int cx1 = min(max(x0 + 1, 0), Wi - 1);
            const int cy0 = min(max(y0, 0), Hi - 1);
            const int cy1 = min(max(y0 + 1, 0), Hi - 1);
            float v00 = 0.f, v10 = 0.f, v01 = 0.f, v11 = 0.f;
            if (vx0 && vy0) v00 = vpm[(size_t)(base + cy0 * Wi + cx0) * 32];
            if (vx1 && vy0) v10 = vpm[(size_t)(base + cy0 * Wi + cx1) * 32];
            if (vx0 && vy1) v01 = vpm[(size_t)(base + cy1 * Wi + cx0) * 32];
            if (vx1 && vy1) v11 = vpm[(size_t)(base + cy1 * Wi + cx1) * 32];
            acc += a * (w00 * v00 + w10 * v10 + w01 * v01 + w11 * v11);
        }
    }
    mid[(size_t)bq * 256 + m * 32 + d] = acc;
}

extern "C" void kernel_launch(void* const* d_in, const int* in_sizes, int n_in,
                              void* d_out, int out_size, void* d_ws, size_t ws_size,
                              hipStream_t stream) {
    const float* q      = (const float*)d_in[0];
    const float* p      = (const float*)d_in[1];
    const float* v      = (const float*)d_in[2];
    // d_in[3] = shapes, d_in[4] = level_index : fixed, hardcoded
    const float* W_off  = (const float*)d_in[5];
    const float* b_off  = (const float*)d_in[6];
    const float* W_attn = (const float*)d_in[7];
    const float* b_attn = (const float*)d_in[8];
    const float* W_val  = (const float*)d_in[9];
    const float* b_val  = (const float*)d_in[10];
    const float* W_out  = (const float*)d_in[11];
    const float* b_out  = (const float*)d_in[12];
    float* out = (float*)d_out;

    // Workspace layout (floats): vp | gattn | goff | mid
    float* vp  = (float*)d_ws;                  // 4*8*21760*32 = 22282240
    float* ga  = vp + (size_t)22282240;         // 16384*128    =  2097152
    float* go  = ga + (size_t)2097152;          // 16384*256    =  4194304
    float* mid = go + (size_t)4194304;          // 16384*256    =  4194304

    // 1) v_p = v @ W_val + b_val  -> [B,8,N,32]
    {
        dim3 grid(256 / 64, NN / 64, BB);       // (4, 340, 4)
        gemm_tile<1><<<grid, 256, 0, stream>>>(v, W_val, b_val, vp, NN, 256, 256);
    }
    // 2) attn logits = q @ W_attn + b_attn -> [B*Q,128]
    {
        dim3 grid(128 / 64, (BB * QQ) / 64, 1); // (2, 256)
        gemm_tile<0><<<grid, 256, 0, stream>>>(q, W_attn, b_attn, ga, BB * QQ, 128, 256);
    }
    // 3) offsets = q @ W_off + b_off -> [B*Q,256]
    {
        dim3 grid(256 / 64, (BB * QQ) / 64, 1); // (4, 256)
        gemm_tile<0><<<grid, 256, 0, stream>>>(q, W_off, b_off, go, BB * QQ, 256, 256);
    }
    // 4) softmax + bilinear sampling -> mid [B*Q,256]
    sampler<<<BB * QQ, 256, 0, stream>>>(vp, ga, go, p, mid);
    // 5) out = mid @ W_out + b_out -> [B,Q,256]
    {
        dim3 grid(256 / 64, (BB * QQ) / 64, 1);
        gemm_tile<0><<<grid, 256, 0, stream>>>(mid, W_out, b_out, out, BB * QQ, 256, 256);
    }
}